// Round 8
// baseline (119.750 us; speedup 1.0000x reference)
//
#include <hip/hip_runtime.h>
#include <math.h>

// Problem constants
#define BB 256
#define NE 400
#define NP (BB * NE)        // 102400 pairs
#define HID 256
#define NCOP 224
#define DIN 480
#define MBLK 64             // pairs per block in fused MFMA kernel
#define NBLK (NP / MBLK)    // 1600

typedef _Float16 half8 __attribute__((ext_vector_type(8)));
typedef _Float16 half4 __attribute__((ext_vector_type(4)));
typedef float f4 __attribute__((ext_vector_type(4)));

static __device__ __forceinline__ float silu_f(float x) {
    return x / (1.0f + __expf(-x));
}

// Swizzled byte offset into the activation LDS buffer.
// Row stride = 512 B (256 f16). XOR row&7 into bits 4..6.
static __device__ __forceinline__ int swz(int row, int colbyte) {
    return (row * 512 + colbyte) ^ ((row & 7) << 4);
}

// ---------------------------------------------------------------------------
// Precompute (fp32):
//  E1[e][n]  = e_feat[e] @ mW1[0:32]                 (400 x 256)
//  F1[b][n]  = field[b] @ mW1[32:96] + mb1           (256 x 256)
//  Fo[b][n]  = field[b] @ oW1[224:288] + ob1         (256 x 256)
//  S[b][c]   = mean(x^2) per copy: l=1 (c<64, dim3), l=2 (c 64..95, dim5)
// ---------------------------------------------------------------------------
__global__ void precompute_kernel(const float* __restrict__ h_abs,
                                  const float* __restrict__ e_feat,
                                  const float* __restrict__ field,
                                  const float* __restrict__ mW1,
                                  const float* __restrict__ mb1,
                                  const float* __restrict__ oW1,
                                  const float* __restrict__ ob1,
                                  float* __restrict__ E1,
                                  float* __restrict__ F1,
                                  float* __restrict__ Fo,
                                  float* __restrict__ S)
{
    int r = blockIdx.x;
    int t = threadIdx.x;
    if (r < NE) {
        float a = 0.f;
        #pragma unroll
        for (int k = 0; k < 32; ++k) a += e_feat[r * 32 + k] * mW1[k * HID + t];
        E1[r * HID + t] = a;
    } else if (r < NE + BB) {
        int b = r - NE;
        float a = mb1[t];
        #pragma unroll
        for (int k = 0; k < 64; ++k) a += field[b * 64 + k] * mW1[(32 + k) * HID + t];
        F1[b * HID + t] = a;
    } else if (r < NE + 2 * BB) {
        int b = r - NE - BB;
        float a = ob1[t];
        #pragma unroll
        for (int k = 0; k < 64; ++k) a += field[b * 64 + k] * oW1[(224 + k) * HID + t];
        Fo[b * HID + t] = a;
    } else {
        int b = r - NE - 2 * BB;
        if (t < 64) {
            const float* x = h_abs + b * DIN + 128 + t * 3;
            S[b * 96 + t] = (x[0]*x[0] + x[1]*x[1] + x[2]*x[2]) * (1.0f / 3.0f);
        } else if (t < 96) {
            int c = t - 64;
            const float* x = h_abs + b * DIN + 320 + c * 5;
            float s = 0.f;
            #pragma unroll
            for (int d = 0; d < 5; ++d) s += x[d] * x[d];
            S[b * 96 + t] = s * 0.2f;
        }
    }
}

// ---------------------------------------------------------------------------
// Pack weights (fp32 -> fp16). Fragment (nt, ks), lane l, elem j holds
// W[ks*32 + (l>>4)*8 + j][nt*16 + (l&15)] -- serves as the MFMA *A* operand
// (rows = output col n) in the swapped-operand scheme.
// ---------------------------------------------------------------------------
__global__ void pack_weights(const float* __restrict__ mW2, const float* __restrict__ mW3,
                             const float* __restrict__ oW1, const float* __restrict__ oW2,
                             _Float16* __restrict__ PB2, _Float16* __restrict__ PB3,
                             _Float16* __restrict__ PO1, _Float16* __restrict__ PO2)
{
    int blk = blockIdx.x;
    int l = threadIdx.x;
    const float* W; _Float16* P; int LD;
    if (blk < 128)      { W = mW2; P = PB2; LD = 256; }
    else if (blk < 240) { blk -= 128; W = mW3; P = PB3; LD = 224; }
    else if (blk < 352) { blk -= 240; W = oW1; P = PO1; LD = 256; }
    else                { blk -= 352; W = oW2; P = PO2; LD = 256; }
    int KST = (P == PO1) ? 7 : 8;
    int nt = blk / KST, ks = blk - nt * KST;
    int n  = nt * 16 + (l & 15);
    int k0 = ks * 32 + (l >> 4) * 8;
    half8 v;
    #pragma unroll
    for (int j = 0; j < 8; ++j) v[j] = (_Float16)W[(size_t)(k0 + j) * LD + n];
    *(half8*)&P[(size_t)(blk * 64 + l) * 8] = v;
}

// ---------------------------------------------------------------------------
// One GEMM phase on the matrix pipe, operands swapped:
//   acc = mfma(W_frag /*A: rows=n*/, act_frag /*B: cols=pair*/, acc)
// => D: lane holds col = pair (lane&15), 4 regs = 4 consecutive n.
// ---------------------------------------------------------------------------
template<int KST, bool TWO>
static __device__ __forceinline__ void mma_phase(const half8* __restrict__ Wp,
                                                 const char* actp, int lane,
                                                 int tile0, f4 acc[4][2])
{
    #pragma unroll
    for (int mt = 0; mt < 4; ++mt) {
        acc[mt][0] = (f4){0.f, 0.f, 0.f, 0.f};
        acc[mt][1] = (f4){0.f, 0.f, 0.f, 0.f};
    }
    const int tile1 = tile0 + 8;

    #pragma unroll
    for (int ks = 0; ks < KST; ++ks) {
        int kb = ks * 64 + ((lane >> 4) << 4);   // (ks*32 + (lane>>4)*8) * 2 bytes
        half8 a[4];
        #pragma unroll
        for (int mt = 0; mt < 4; ++mt) {
            int row = mt * 16 + (lane & 15);
            a[mt] = *(const half8*)(actp + ((row * 512 + kb) ^ ((row & 7) << 4)));
        }
        half8 b0 = Wp[(tile0 * KST + ks) * 64 + lane];
        #pragma unroll
        for (int mt = 0; mt < 4; ++mt)
            acc[mt][0] = __builtin_amdgcn_mfma_f32_16x16x32_f16(b0, a[mt], acc[mt][0], 0, 0, 0);
        if (TWO) {
            half8 b1 = Wp[(tile1 * KST + ks) * 64 + lane];
            #pragma unroll
            for (int mt = 0; mt < 4; ++mt)
                acc[mt][1] = __builtin_amdgcn_mfma_f32_16x16x32_f16(b1, a[mt], acc[mt][1], 0, 0, 0);
        }
    }
}

// ---------------------------------------------------------------------------
// Fused kernel: 64 pairs / block, 512 threads (8 waves).
// SINGLE 32 KB act buffer (in-place epilogues, 2 barriers/phase) so 4 blocks
// fit per CU (round 7's 64 KB dbuf capped residency at 2 blocks -> 36% occ,
// latency-stall dominated).
// ---------------------------------------------------------------------------
__global__ __launch_bounds__(512, 1)
void fused_mfma(const float* __restrict__ h_abs,
                const float* __restrict__ mb2, const float* __restrict__ mb3,
                const float* __restrict__ ob2,
                const float* __restrict__ oW3, const float* __restrict__ ob3,
                const float* __restrict__ E1, const float* __restrict__ F1,
                const float* __restrict__ Fo, const float* __restrict__ S,
                const half8* __restrict__ PB2, const half8* __restrict__ PB3,
                const half8* __restrict__ PO1, const half8* __restrict__ PO2,
                float* __restrict__ out)
{
    __shared__ char act[MBLK * 512];   // 32 KB f16 activations [64][256]

    const int t    = threadIdx.x;
    const int lane = t & 63;
    const int w    = t >> 6;           // 0..7
    const int p0   = blockIdx.x * MBLK;
    const int lr   = lane & 15;
    const int lq   = lane >> 4;

    // Per-block batch decomposition: p = p0+row, b = b0 + (r0+row >= NE).
    // Avoids per-use integer division by 400 (magic-mul chains).
    const int b0 = p0 / NE;
    const int r0 = p0 - b0 * NE;

    // ---- Phase A: h1 = silu(E1[e] + F1[b])  -> act (f16) ----
    {
        #pragma unroll
        for (int i = 0; i < 4; ++i) {
            int c   = i * 512 + t;        // 0..2047 chunk id
            int row = c >> 5;
            int c0  = (c & 31) * 8;
            int e = r0 + row;
            int b = b0;
            if (e >= NE) { e -= NE; b += 1; }
            const f4* ep = (const f4*)&E1[e * HID + c0];
            const f4* fp = (const f4*)&F1[b * HID + c0];
            f4 e0 = ep[0], e1 = ep[1];
            f4 f0 = fp[0], f1 = fp[1];
            half8 hv;
            #pragma unroll
            for (int j = 0; j < 4; ++j) hv[j]     = (_Float16)silu_f(e0[j] + f0[j]);
            #pragma unroll
            for (int j = 0; j < 4; ++j) hv[4 + j] = (_Float16)silu_f(e1[j] + f1[j]);
            *(half8*)(act + swz(row, c0 * 2)) = hv;
        }
    }
    __syncthreads();

    f4 acc[4][2];

    // ---- Phase B: h2 = silu(h1 @ mW2 + mb2)  [in-place] ----
    mma_phase<8, true>(PB2, act, lane, w, acc);
    __syncthreads();   // all reads of h1 done
    #pragma unroll
    for (int ntj = 0; ntj < 2; ++ntj) {
        int n0 = (w + ntj * 8) * 16 + lq * 4;
        f4 bias = *(const f4*)&mb2[n0];
        #pragma unroll
        for (int mt = 0; mt < 4; ++mt) {
            int row = mt * 16 + lr;
            half4 hv;
            #pragma unroll
            for (int r = 0; r < 4; ++r)
                hv[r] = (_Float16)silu_f(acc[mt][ntj][r] + bias[r]);
            *(half4*)(act + swz(row, n0 * 2)) = hv;
        }
    }
    __syncthreads();   // h2 visible

    // ---- Phase C: g = h2 @ mW3 + mb3 ; invariant  [in-place, cols 0..223] ----
    if (w < 6) mma_phase<8, true >(PB3, act, lane, w, acc);
    else       mma_phase<8, false>(PB3, act, lane, w, acc);
    __syncthreads();
    #pragma unroll
    for (int ntj = 0; ntj < 2; ++ntj) {
        int tile = w + ntj * 8;
        if (tile < 14) {
            int n0 = tile * 16 + lq * 4;
            f4 bias = *(const f4*)&mb3[n0];
            #pragma unroll
            for (int mt = 0; mt < 4; ++mt) {
                int row = mt * 16 + lr;
                int b = b0 + ((r0 + row) >= NE);
                half4 hv;
                if (n0 < 128) {
                    f4 xh = *(const f4*)&h_abs[b * DIN + n0];
                    #pragma unroll
                    for (int r = 0; r < 4; ++r)
                        hv[r] = (_Float16)(xh[r] * (acc[mt][ntj][r] + bias[r]));
                } else {
                    f4 sv = *(const f4*)&S[b * 96 + (n0 - 128)];
                    #pragma unroll
                    for (int r = 0; r < 4; ++r) {
                        float g = acc[mt][ntj][r] + bias[r];
                        hv[r] = (_Float16)sqrtf(g * g * sv[r] + 1e-8f);
                    }
                }
                *(half4*)(act + swz(row, n0 * 2)) = hv;
            }
        }
    }
    __syncthreads();

    // ---- Phase D: o1 = silu(inv @ oW1[0:224] + Fo[b])  [in-place] ----
    mma_phase<7, true>(PO1, act, lane, w, acc);
    __syncthreads();
    #pragma unroll
    for (int ntj = 0; ntj < 2; ++ntj) {
        int n0 = (w + ntj * 8) * 16 + lq * 4;
        #pragma unroll
        for (int mt = 0; mt < 4; ++mt) {
            int row = mt * 16 + lr;
            int b = b0 + ((r0 + row) >= NE);
            f4 fo = *(const f4*)&Fo[b * HID + n0];
            half4 hv;
            #pragma unroll
            for (int r = 0; r < 4; ++r)
                hv[r] = (_Float16)silu_f(acc[mt][ntj][r] + fo[r]);
            *(half4*)(act + swz(row, n0 * 2)) = hv;
        }
    }
    __syncthreads();

    // ---- Phase E: o2 = silu(o1 @ oW2 + ob2)  [in-place] ----
    mma_phase<8, true>(PO2, act, lane, w, acc);
    __syncthreads();
    #pragma unroll
    for (int ntj = 0; ntj < 2; ++ntj) {
        int n0 = (w + ntj * 8) * 16 + lq * 4;
        f4 bias = *(const f4*)&ob2[n0];
        #pragma unroll
        for (int mt = 0; mt < 4; ++mt) {
            int row = mt * 16 + lr;
            half4 hv;
            #pragma unroll
            for (int r = 0; r < 4; ++r)
                hv[r] = (_Float16)silu_f(acc[mt][ntj][r] + bias[r]);
            *(half4*)(act + swz(row, n0 * 2)) = hv;
        }
    }
    __syncthreads();

    // ---- Phase F: out[p] = o2[p] . oW3 + ob3  (fp32 dot, 8 threads/pair) ----
    {
        int pF  = t >> 3;   // 0..63
        int seg = t & 7;    // 0..7, each covers 32 f16 = 4 x 16B chunks
        float s = 0.f;
        #pragma unroll
        for (int q = 0; q < 4; ++q) {
            half8 v = *(const half8*)(act + swz(pF, seg * 64 + q * 16));
            const f4* wp = (const f4*)&oW3[seg * 32 + q * 8];
            f4 wa = wp[0], wb = wp[1];
            #pragma unroll
            for (int j = 0; j < 4; ++j) s += (float)v[j]     * wa[j];
            #pragma unroll
            for (int j = 0; j < 4; ++j) s += (float)v[4 + j] * wb[j];
        }
        s += __shfl_xor(s, 1, 64);
        s += __shfl_xor(s, 2, 64);
        s += __shfl_xor(s, 4, 64);
        if (seg == 0) out[p0 + pF] = s + ob3[0];
    }
}

extern "C" void kernel_launch(void* const* d_in, const int* in_sizes, int n_in,
                              void* d_out, int out_size, void* d_ws, size_t ws_size,
                              hipStream_t stream) {
    const float* h_abs  = (const float*)d_in[0];
    const float* e_feat = (const float*)d_in[1];
    const float* field  = (const float*)d_in[2];
    const float* mW1 = (const float*)d_in[3];
    const float* mb1 = (const float*)d_in[4];
    const float* mW2 = (const float*)d_in[5];
    const float* mb2 = (const float*)d_in[6];
    const float* mW3 = (const float*)d_in[7];
    const float* mb3 = (const float*)d_in[8];
    const float* oW1 = (const float*)d_in[9];
    const float* ob1 = (const float*)d_in[10];
    const float* oW2 = (const float*)d_in[11];
    const float* ob2 = (const float*)d_in[12];
    const float* oW3 = (const float*)d_in[13];
    const float* ob3 = (const float*)d_in[14];
    float* out = (float*)d_out;

    // Workspace layout
    float* ws = (float*)d_ws;
    float* E1 = ws;                      // 400*256 = 102400 f
    float* F1 = E1 + NE * HID;           // 65536 f
    float* Fo = F1 + BB * HID;           // 65536 f
    float* S  = Fo + BB * HID;           // 24576 f
    _Float16* PB2 = (_Float16*)(S + BB * 96);   // 16*8*64*8 = 65536 h
    _Float16* PB3 = PB2 + 16 * 8 * 64 * 8;      // 14*8*64*8 = 57344 h
    _Float16* PO1 = PB3 + 14 * 8 * 64 * 8;      // 16*7*64*8 = 57344 h
    _Float16* PO2 = PO1 + 16 * 7 * 64 * 8;      // 16*8*64*8 = 65536 h

    precompute_kernel<<<NE + 3 * BB, 256, 0, stream>>>(
        h_abs, e_feat, field, mW1, mb1, oW1, ob1, E1, F1, Fo, S);

    pack_weights<<<480, 64, 0, stream>>>(
        mW2, mW3, oW1, oW2, PB2, PB3, PO1, PO2);

    fused_mfma<<<NBLK, 512, 0, stream>>>(
        h_abs, mb2, mb3, ob2, oW3, ob3,
        E1, F1, Fo, S,
        (const half8*)PB2, (const half8*)PB3, (const half8*)PO1, (const half8*)PO2,
        out);
}

// Round 9
// 111.488 us; speedup vs baseline: 1.0741x; 1.0741x over previous
//
#include <hip/hip_runtime.h>
#include <math.h>

// Problem constants
#define BB 256
#define NE 400
#define NP (BB * NE)        // 102400 pairs
#define HID 256
#define NCOP 224
#define DIN 480
#define MBLK 64             // pairs per block in fused MFMA kernel
#define NBLK (NP / MBLK)    // 1600

typedef _Float16 half8 __attribute__((ext_vector_type(8)));
typedef _Float16 half4 __attribute__((ext_vector_type(4)));
typedef float f4 __attribute__((ext_vector_type(4)));

static __device__ __forceinline__ float silu_f(float x) {
    return x / (1.0f + __expf(-x));
}

// Swizzled byte offset into the activation LDS buffer.
// Row stride = 512 B (256 f16). XOR row&7 into bits 4..6.
static __device__ __forceinline__ int swz(int row, int colbyte) {
    return (row * 512 + colbyte) ^ ((row & 7) << 4);
}

// ---------------------------------------------------------------------------
// Precompute (fp32):
//  E1[e][n]  = e_feat[e] @ mW1[0:32]                 (400 x 256)
//  F1[b][n]  = field[b] @ mW1[32:96] + mb1           (256 x 256)
//  Fo[b][n]  = field[b] @ oW1[224:288] + ob1         (256 x 256)
//  S[b][c]   = mean(x^2) per copy: l=1 (c<64, dim3), l=2 (c 64..95, dim5)
// ---------------------------------------------------------------------------
__global__ void precompute_kernel(const float* __restrict__ h_abs,
                                  const float* __restrict__ e_feat,
                                  const float* __restrict__ field,
                                  const float* __restrict__ mW1,
                                  const float* __restrict__ mb1,
                                  const float* __restrict__ oW1,
                                  const float* __restrict__ ob1,
                                  float* __restrict__ E1,
                                  float* __restrict__ F1,
                                  float* __restrict__ Fo,
                                  float* __restrict__ S)
{
    int r = blockIdx.x;
    int t = threadIdx.x;
    if (r < NE) {
        float a = 0.f;
        #pragma unroll
        for (int k = 0; k < 32; ++k) a += e_feat[r * 32 + k] * mW1[k * HID + t];
        E1[r * HID + t] = a;
    } else if (r < NE + BB) {
        int b = r - NE;
        float a = mb1[t];
        #pragma unroll
        for (int k = 0; k < 64; ++k) a += field[b * 64 + k] * mW1[(32 + k) * HID + t];
        F1[b * HID + t] = a;
    } else if (r < NE + 2 * BB) {
        int b = r - NE - BB;
        float a = ob1[t];
        #pragma unroll
        for (int k = 0; k < 64; ++k) a += field[b * 64 + k] * oW1[(224 + k) * HID + t];
        Fo[b * HID + t] = a;
    } else {
        int b = r - NE - 2 * BB;
        if (t < 64) {
            const float* x = h_abs + b * DIN + 128 + t * 3;
            S[b * 96 + t] = (x[0]*x[0] + x[1]*x[1] + x[2]*x[2]) * (1.0f / 3.0f);
        } else if (t < 96) {
            int c = t - 64;
            const float* x = h_abs + b * DIN + 320 + c * 5;
            float s = 0.f;
            #pragma unroll
            for (int d = 0; d < 5; ++d) s += x[d] * x[d];
            S[b * 96 + t] = s * 0.2f;
        }
    }
}

// ---------------------------------------------------------------------------
// Pack weights (fp32 -> fp16). Fragment (nt, ks), lane l, elem j holds
// W[ks*32 + (l>>4)*8 + j][nt*16 + (l&15)] -- serves as the MFMA *A* operand
// (rows = output col n) in the swapped-operand scheme.
// ---------------------------------------------------------------------------
__global__ void pack_weights(const float* __restrict__ mW2, const float* __restrict__ mW3,
                             const float* __restrict__ oW1, const float* __restrict__ oW2,
                             _Float16* __restrict__ PB2, _Float16* __restrict__ PB3,
                             _Float16* __restrict__ PO1, _Float16* __restrict__ PO2)
{
    int blk = blockIdx.x;
    int l = threadIdx.x;
    const float* W; _Float16* P; int LD;
    if (blk < 128)      { W = mW2; P = PB2; LD = 256; }
    else if (blk < 240) { blk -= 128; W = mW3; P = PB3; LD = 224; }
    else if (blk < 352) { blk -= 240; W = oW1; P = PO1; LD = 256; }
    else                { blk -= 352; W = oW2; P = PO2; LD = 256; }
    int KST = (P == PO1) ? 7 : 8;
    int nt = blk / KST, ks = blk - nt * KST;
    int n  = nt * 16 + (l & 15);
    int k0 = ks * 32 + (l >> 4) * 8;
    half8 v;
    #pragma unroll
    for (int j = 0; j < 8; ++j) v[j] = (_Float16)W[(size_t)(k0 + j) * LD + n];
    *(half8*)&P[(size_t)(blk * 64 + l) * 8] = v;
}

// ---------------------------------------------------------------------------
// One GEMM phase on the matrix pipe, operands swapped:
//   acc = mfma(W_frag /*A: rows=n*/, act_frag /*B: cols=pair*/, acc)
// => D: lane holds col = pair (lane&15), 4 regs = 4 consecutive n.
// ALL weight fragments are loaded into registers up-front (one batched issue,
// latency hidden under the ds_read+MFMA chain) -- round 8 issued them JIT
// inside the ks loop and serially exposed L2 latency each iteration.
// ---------------------------------------------------------------------------
template<int KST, bool TWO>
static __device__ __forceinline__ void mma_phase(const half8* __restrict__ Wp,
                                                 const char* actp, int lane,
                                                 int tile0, f4 acc[4][2])
{
    half8 bf0[KST], bf1[TWO ? KST : 1];
    #pragma unroll
    for (int ks = 0; ks < KST; ++ks)
        bf0[ks] = Wp[(tile0 * KST + ks) * 64 + lane];
    if (TWO) {
        #pragma unroll
        for (int ks = 0; ks < KST; ++ks)
            bf1[ks] = Wp[((tile0 + 8) * KST + ks) * 64 + lane];
    }

    #pragma unroll
    for (int mt = 0; mt < 4; ++mt) {
        acc[mt][0] = (f4){0.f, 0.f, 0.f, 0.f};
        acc[mt][1] = (f4){0.f, 0.f, 0.f, 0.f};
    }

    #pragma unroll
    for (int ks = 0; ks < KST; ++ks) {
        int kb = ks * 64 + ((lane >> 4) << 4);   // (ks*32 + (lane>>4)*8) * 2 bytes
        half8 a[4];
        #pragma unroll
        for (int mt = 0; mt < 4; ++mt) {
            int row = mt * 16 + (lane & 15);
            a[mt] = *(const half8*)(actp + ((row * 512 + kb) ^ ((row & 7) << 4)));
        }
        #pragma unroll
        for (int mt = 0; mt < 4; ++mt)
            acc[mt][0] = __builtin_amdgcn_mfma_f32_16x16x32_f16(bf0[ks], a[mt], acc[mt][0], 0, 0, 0);
        if (TWO) {
            #pragma unroll
            for (int mt = 0; mt < 4; ++mt)
                acc[mt][1] = __builtin_amdgcn_mfma_f32_16x16x32_f16(bf1[ks], a[mt], acc[mt][1], 0, 0, 0);
        }
    }
}

// ---------------------------------------------------------------------------
// Fused kernel: 64 pairs / block, 512 threads (8 waves).
// Single 32 KB act buffer; phases E+F fused in-register (no o2 LDS round-trip).
// ---------------------------------------------------------------------------
__global__ __launch_bounds__(512, 1)
void fused_mfma(const float* __restrict__ h_abs,
                const float* __restrict__ mb2, const float* __restrict__ mb3,
                const float* __restrict__ ob2,
                const float* __restrict__ oW3, const float* __restrict__ ob3,
                const float* __restrict__ E1, const float* __restrict__ F1,
                const float* __restrict__ Fo, const float* __restrict__ S,
                const half8* __restrict__ PB2, const half8* __restrict__ PB3,
                const half8* __restrict__ PO1, const half8* __restrict__ PO2,
                float* __restrict__ out)
{
    __shared__ char act[MBLK * 512];   // 32 KB f16 activations [64][256]
    __shared__ float sred[8][64];      // 2 KB cross-wave partial sums (E+F fusion)

    const int t    = threadIdx.x;
    const int lane = t & 63;
    const int w    = t >> 6;           // 0..7
    const int p0   = blockIdx.x * MBLK;
    const int lr   = lane & 15;
    const int lq   = lane >> 4;

    // p = p0+row, b = b0 + (r0+row >= NE): avoids per-use int division by 400.
    const int b0 = p0 / NE;
    const int r0 = p0 - b0 * NE;

    // ---- Phase A: h1 = silu(E1[e] + F1[b])  -> act (f16) ----
    {
        #pragma unroll
        for (int i = 0; i < 4; ++i) {
            int c   = i * 512 + t;        // 0..2047 chunk id
            int row = c >> 5;
            int c0  = (c & 31) * 8;
            int e = r0 + row;
            int b = b0;
            if (e >= NE) { e -= NE; b += 1; }
            const f4* ep = (const f4*)&E1[e * HID + c0];
            const f4* fp = (const f4*)&F1[b * HID + c0];
            f4 e0 = ep[0], e1 = ep[1];
            f4 f0 = fp[0], f1 = fp[1];
            half8 hv;
            #pragma unroll
            for (int j = 0; j < 4; ++j) hv[j]     = (_Float16)silu_f(e0[j] + f0[j]);
            #pragma unroll
            for (int j = 0; j < 4; ++j) hv[4 + j] = (_Float16)silu_f(e1[j] + f1[j]);
            *(half8*)(act + swz(row, c0 * 2)) = hv;
        }
    }
    __syncthreads();

    f4 acc[4][2];

    // ---- Phase B: h2 = silu(h1 @ mW2 + mb2)  [in-place] ----
    mma_phase<8, true>(PB2, act, lane, w, acc);
    __syncthreads();   // all reads of h1 done
    #pragma unroll
    for (int ntj = 0; ntj < 2; ++ntj) {
        int n0 = (w + ntj * 8) * 16 + lq * 4;
        f4 bias = *(const f4*)&mb2[n0];
        #pragma unroll
        for (int mt = 0; mt < 4; ++mt) {
            int row = mt * 16 + lr;
            half4 hv;
            #pragma unroll
            for (int r = 0; r < 4; ++r)
                hv[r] = (_Float16)silu_f(acc[mt][ntj][r] + bias[r]);
            *(half4*)(act + swz(row, n0 * 2)) = hv;
        }
    }
    __syncthreads();   // h2 visible

    // ---- Phase C: g = h2 @ mW3 + mb3 ; invariant  [in-place, cols 0..223] ----
    if (w < 6) mma_phase<8, true >(PB3, act, lane, w, acc);
    else       mma_phase<8, false>(PB3, act, lane, w, acc);
    __syncthreads();
    #pragma unroll
    for (int ntj = 0; ntj < 2; ++ntj) {
        int tile = w + ntj * 8;
        if (tile < 14) {
            int n0 = tile * 16 + lq * 4;
            f4 bias = *(const f4*)&mb3[n0];
            #pragma unroll
            for (int mt = 0; mt < 4; ++mt) {
                int row = mt * 16 + lr;
                int b = b0 + ((r0 + row) >= NE);
                half4 hv;
                if (n0 < 128) {
                    f4 xh = *(const f4*)&h_abs[b * DIN + n0];
                    #pragma unroll
                    for (int r = 0; r < 4; ++r)
                        hv[r] = (_Float16)(xh[r] * (acc[mt][ntj][r] + bias[r]));
                } else {
                    f4 sv = *(const f4*)&S[b * 96 + (n0 - 128)];
                    #pragma unroll
                    for (int r = 0; r < 4; ++r) {
                        float g = acc[mt][ntj][r] + bias[r];
                        hv[r] = (_Float16)sqrtf(g * g * sv[r] + 1e-8f);
                    }
                }
                *(half4*)(act + swz(row, n0 * 2)) = hv;
            }
        }
    }
    __syncthreads();

    // ---- Phase D: o1 = silu(inv @ oW1[0:224] + Fo[b])  [in-place] ----
    mma_phase<7, true>(PO1, act, lane, w, acc);
    __syncthreads();
    #pragma unroll
    for (int ntj = 0; ntj < 2; ++ntj) {
        int n0 = (w + ntj * 8) * 16 + lq * 4;
        #pragma unroll
        for (int mt = 0; mt < 4; ++mt) {
            int row = mt * 16 + lr;
            int b = b0 + ((r0 + row) >= NE);
            f4 fo = *(const f4*)&Fo[b * HID + n0];
            half4 hv;
            #pragma unroll
            for (int r = 0; r < 4; ++r)
                hv[r] = (_Float16)silu_f(acc[mt][ntj][r] + fo[r]);
            *(half4*)(act + swz(row, n0 * 2)) = hv;
        }
    }
    __syncthreads();

    // ---- Phase E+F fused: out[p] = silu(o1 @ oW2 + ob2) . oW3 + ob3 ----
    // Lane holds o2 values for pair (mt*16+lr) at n = (w+8ntj)*16+lq*4+r:
    // dot with oW3 in-register, reduce over lq (shfl), cross-wave via sred.
    mma_phase<8, true>(PO2, act, lane, w, acc);
    {
        float partial[4] = {0.f, 0.f, 0.f, 0.f};
        #pragma unroll
        for (int ntj = 0; ntj < 2; ++ntj) {
            int n0 = (w + ntj * 8) * 16 + lq * 4;
            f4 bias = *(const f4*)&ob2[n0];
            f4 wv   = *(const f4*)&oW3[n0];
            #pragma unroll
            for (int mt = 0; mt < 4; ++mt)
                #pragma unroll
                for (int r = 0; r < 4; ++r)
                    partial[mt] += silu_f(acc[mt][ntj][r] + bias[r]) * wv[r];
        }
        #pragma unroll
        for (int mt = 0; mt < 4; ++mt) {
            float s = partial[mt];
            s += __shfl_xor(s, 16, 64);
            s += __shfl_xor(s, 32, 64);
            if (lq == 0) sred[w][mt * 16 + lr] = s;
        }
    }
    __syncthreads();
    if (t < 64) {
        float s = ob3[0];
        #pragma unroll
        for (int ww = 0; ww < 8; ++ww) s += sred[ww][t];
        out[p0 + t] = s;
    }
}

extern "C" void kernel_launch(void* const* d_in, const int* in_sizes, int n_in,
                              void* d_out, int out_size, void* d_ws, size_t ws_size,
                              hipStream_t stream) {
    const float* h_abs  = (const float*)d_in[0];
    const float* e_feat = (const float*)d_in[1];
    const float* field  = (const float*)d_in[2];
    const float* mW1 = (const float*)d_in[3];
    const float* mb1 = (const float*)d_in[4];
    const float* mW2 = (const float*)d_in[5];
    const float* mb2 = (const float*)d_in[6];
    const float* mW3 = (const float*)d_in[7];
    const float* mb3 = (const float*)d_in[8];
    const float* oW1 = (const float*)d_in[9];
    const float* ob1 = (const float*)d_in[10];
    const float* oW2 = (const float*)d_in[11];
    const float* ob2 = (const float*)d_in[12];
    const float* oW3 = (const float*)d_in[13];
    const float* ob3 = (const float*)d_in[14];
    float* out = (float*)d_out;

    // Workspace layout
    float* ws = (float*)d_ws;
    float* E1 = ws;                      // 400*256 = 102400 f
    float* F1 = E1 + NE * HID;           // 65536 f
    float* Fo = F1 + BB * HID;           // 65536 f
    float* S  = Fo + BB * HID;           // 24576 f
    _Float16* PB2 = (_Float16*)(S + BB * 96);   // 16*8*64*8 = 65536 h
    _Float16* PB3 = PB2 + 16 * 8 * 64 * 8;      // 14*8*64*8 = 57344 h
    _Float16* PO1 = PB3 + 14 * 8 * 64 * 8;      // 16*7*64*8 = 57344 h
    _Float16* PO2 = PO1 + 16 * 7 * 64 * 8;      // 16*8*64*8 = 65536 h

    precompute_kernel<<<NE + 3 * BB, 256, 0, stream>>>(
        h_abs, e_feat, field, mW1, mb1, oW1, ob1, E1, F1, Fo, S);

    pack_weights<<<480, 64, 0, stream>>>(
        mW2, mW3, oW1, oW2, PB2, PB3, PO1, PO2);

    fused_mfma<<<NBLK, 512, 0, stream>>>(
        h_abs, mb2, mb3, ob2, oW3, ob3,
        E1, F1, Fo, S,
        (const half8*)PB2, (const half8*)PB3, (const half8*)PO1, (const half8*)PO2,
        out);
}